// Round 5
// baseline (223.669 us; speedup 1.0000x reference)
//
#include <hip/hip_runtime.h>
#include <hip/hip_bf16.h>

#define IMG   224
#define HO    112
#define WO_   112
#define EMBED 192
#define BATCH 32
#define ROWS  2            // patch rows per block

// One block: ROWS=2 patch-rows of one batch image.
// Phase 1: threads 0..223 compute per-patch (offx, offy) into LDS.
// Phase 2: all 256 threads resample 2*112*16*3 = 10752 output pixels (fp32 out).
__global__ __launch_bounds__(256)
void fused_kernel(const float* __restrict__ x,
                  const float* __restrict__ conv_w,
                  const float* __restrict__ conv_b,
                  const float* __restrict__ off_w,
                  float* __restrict__ out) {
    __shared__ float s_off[ROWS * WO_ * 2];

    int b   = blockIdx.x / (HO / ROWS);
    int ho0 = (blockIdx.x % (HO / ROWS)) * ROWS;
    int t   = threadIdx.x;

    // ---- Phase 1: conv3x3-s2 (192 ch) -> exact GELU -> 2-dim projection ----
    if (t < ROWS * WO_) {
        int wo = t % WO_;
        int ho = ho0 + t / WO_;

        float xv[27];
        int iy0 = 2 * ho - 1, ix0 = 2 * wo - 1;
#pragma unroll
        for (int c = 0; c < 3; ++c) {
            const float* xc = x + ((size_t)(b * 3 + c)) * IMG * IMG;
#pragma unroll
            for (int ky = 0; ky < 3; ++ky) {
                int iy = iy0 + ky;
#pragma unroll
                for (int kx = 0; kx < 3; ++kx) {
                    int ix = ix0 + kx;
                    float v = 0.0f;
                    if (iy >= 0 && iy < IMG && ix >= 0 && ix < IMG)
                        v = xc[iy * IMG + ix];
                    xv[c * 9 + ky * 3 + kx] = v;
                }
            }
        }

        float offx = 0.0f, offy = 0.0f;
        for (int e = 0; e < EMBED; ++e) {
            const float* wr = conv_w + e * 27;   // wave-uniform -> scalar loads
            float acc = conv_b[e];
#pragma unroll
            for (int i = 0; i < 27; ++i) acc = fmaf(wr[i], xv[i], acc);
            // exact GELU: 0.5*x*(1+erf(x/sqrt(2)))
            float g = 0.5f * acc * (1.0f + erff(acc * 0.70710678118654752f));
            offx = fmaf(g, off_w[e], offx);
            offy = fmaf(g, off_w[EMBED + e], offy);
        }
        s_off[t * 2 + 0] = offx * 2.0f;   // * PATCH_SIZE
        s_off[t * 2 + 1] = offy * 2.0f;
    }
    __syncthreads();

    // ---- Phase 2: resample; idx = ox(448) + 448*(py(4) + 4*(hrow(2) + 2*c(3)))
    for (int k = 0; k < 42; ++k) {
        int idx = k * 256 + t;
        int ox  = idx % 448;
        int r   = idx / 448;
        int py  = r % 4;
        int r2  = r / 4;
        int hrow = r2 % ROWS;
        int c    = r2 / ROWS;

        int ho = ho0 + hrow;
        int wo = ox >> 2, px = ox & 3;

        float ofx = s_off[(hrow * WO_ + wo) * 2 + 0];
        float ofy = s_off[(hrow * WO_ + wo) * 2 + 1];

        float ys = (ho + 0.5f) * 2.0f + ofy + ((py + 0.5f) * 0.5f - 1.0f);
        float xs = (wo + 0.5f) * 2.0f + ofx + ((px + 0.5f) * 0.5f - 1.0f);

        float y0f = floorf(ys), x0f = floorf(xs);
        float wy = ys - y0f, wx = xs - x0f;
        int y0 = (int)y0f; y0 = min(max(y0, 0), IMG - 1);
        int x0 = (int)x0f; x0 = min(max(x0, 0), IMG - 1);
        int y1 = min(y0 + 1, IMG - 1);
        int x1 = min(x0 + 1, IMG - 1);

        const float* xc = x + ((size_t)(b * 3 + c)) * IMG * IMG;
        float v00 = xc[y0 * IMG + x0];
        float v01 = xc[y0 * IMG + x1];
        float v10 = xc[y1 * IMG + x0];
        float v11 = xc[y1 * IMG + x1];

        float rv = v00 * (1.0f - wy) * (1.0f - wx) + v01 * (1.0f - wy) * wx
                 + v10 * wy * (1.0f - wx)          + v11 * wy * wx;

        int oy = ho * 4 + py;
        // fp32 output — the reference's output dtype is float32.
        out[((size_t)(b * 3 + c) * 448 + oy) * 448 + ox] = rv;
    }
}

extern "C" void kernel_launch(void* const* d_in, const int* in_sizes, int n_in,
                              void* d_out, int out_size, void* d_ws, size_t ws_size,
                              hipStream_t stream) {
    const float* x      = (const float*)d_in[0];
    const float* conv_w = (const float*)d_in[1];
    const float* conv_b = (const float*)d_in[2];
    const float* off_w  = (const float*)d_in[3];
    float* out = (float*)d_out;

    int grid = BATCH * (HO / ROWS);   // 32 * 56 = 1792 blocks
    fused_kernel<<<grid, 256, 0, stream>>>(x, conv_w, conv_b, off_w, out);
}